// Round 4
// baseline (620.532 us; speedup 1.0000x reference)
//
#include <hip/hip_runtime.h>
#include <cstdint>
#include <cstddef>

// Sizes (fixed by the reference)
#define B_    32
#define CIN_  32
#define COUT_ 32
#define HH    128
#define WW    128
#define CDIM  256
#define NP    9216     // CIN*COUT*3*3
#define HID   4608
#define KS2   8
#define KPER2 (HID/KS2)   // 576

// ---------------- Kernel 1: ht[j][b] = relu(cond[b] . W1[j] + b1[j]) ----------------
// NOTE: writes h TRANSPOSED [k][b] so mlp2 can read each k-row as wave-uniform
// scalar loads (s_load_dwordx16) with zero LDS.
__global__ __launch_bounds__(256)
void mlp1_k(const float* __restrict__ cond, const float* __restrict__ W1,
            const float* __restrict__ b1, float* __restrict__ ht) {
    __shared__ float cs[CDIM];
    const int b  = blockIdx.x / (HID/256);
    const int jb = blockIdx.x % (HID/256);
    const int tid = threadIdx.x;
    cs[tid] = cond[b*CDIM + tid];
    __syncthreads();
    const int j = jb*256 + tid;
    const float4* wr = reinterpret_cast<const float4*>(W1 + (size_t)j*CDIM);
    float acc = b1[j];
    #pragma unroll 4
    for (int c = 0; c < CDIM/4; ++c) {
        float4 w = wr[c];
        acc += w.x*cs[4*c] + w.y*cs[4*c+1] + w.z*cs[4*c+2] + w.w*cs[4*c+3];
    }
    ht[(size_t)j*B_ + b] = fmaxf(acc, 0.f);   // scattered 4B, L2-merged (tiny)
}

// ---------------- Kernel 2: part[ks][b][p] = sum_{k in split} ht[k][b]*W2[p][k] ------
// Thread = one W2 row p. NO LDS. W2 streamed global->reg (lanes walk their own
// rows; 128B lines amortize over k via L1). h read wave-uniform -> scalar loads,
// A/B double-buffered. acc[32 batches] in VGPRs. 1152 one-wave blocks (~4.5/CU).
__global__ __launch_bounds__(64)
void mlp2_k(const float* __restrict__ ht, const float* __restrict__ W2,
            float* __restrict__ part) {
    const int pblk = blockIdx.x >> 3;       // 144 p-blocks
    const int ks   = blockIdx.x & 7;
    const int p    = pblk*64 + threadIdx.x;
    const int k0   = ks * KPER2;
    const float* w2row = W2 + (size_t)p*HID + k0;
    const float* hrow  = ht + (size_t)k0*B_;
    float acc[B_];
    #pragma unroll
    for (int b = 0; b < B_; ++b) acc[b] = 0.f;
    float hA[B_], hB[B_];
    #pragma unroll
    for (int b = 0; b < B_; ++b) hA[b] = hrow[b];
    for (int k = 0; k < KPER2; k += 2) {
        const float2 wv = *reinterpret_cast<const float2*>(w2row + k);
        #pragma unroll
        for (int b = 0; b < B_; ++b) hB[b] = hrow[(k+1)*B_ + b];
        #pragma unroll
        for (int b = 0; b < B_; ++b) acc[b] = fmaf(hA[b], wv.x, acc[b]);
        #pragma unroll
        for (int b = 0; b < B_; ++b) hA[b] = hrow[(k+2)*B_ + b];  // prefetch (pad covers tail)
        #pragma unroll
        for (int b = 0; b < B_; ++b) acc[b] = fmaf(hB[b], wv.y, acc[b]);
    }
    float* dst = part + (size_t)ks*B_*NP + p;
    #pragma unroll
    for (int b = 0; b < B_; ++b) dst[(size_t)b*NP] = acc[b];   // coalesced over lanes
}

// ---------------- Kernel 3: wt[b][ci*9+k9][co] = sum_ks part[ks][b][p] + b2[p] -------
__global__ __launch_bounds__(256)
void reduce_k(const float* __restrict__ part, const float* __restrict__ b2,
              float* __restrict__ wt) {
    const int idx = blockIdx.x*256 + threadIdx.x;          // quad index < 73728
    const float4* p4 = reinterpret_cast<const float4*>(part);
    const size_t stride = (size_t)B_*NP/4;
    const int pq = idx % (NP/4);
    const int bi = idx / (NP/4);
    float4 bb = reinterpret_cast<const float4*>(b2)[pq];
    float o0 = bb.x, o1 = bb.y, o2 = bb.z, o3 = bb.w;
    #pragma unroll
    for (int s = 0; s < KS2; ++s) {
        float4 v = p4[idx + (size_t)s*stride];
        o0 += v.x; o1 += v.y; o2 += v.z; o3 += v.w;
    }
    const int p  = pq << 2;
    const int co = p / 288;            // 288 = CIN_*9; quad never crosses co boundary
    const int r  = p - co*288;         // r..r+3 = ci*9+k9 consecutive
    float* dst = wt + (size_t)bi*NP + r*32 + co;
    dst[0]  = o0;                      // stride-128B scatter; L2-merged (wt = 1.2MB)
    dst[32] = o1;
    dst[64] = o2;
    dst[96] = o3;
}

// ---------------- Kernel 4: per-sample 3x3 conv (pad 1, stride 1) ----------------
// Block = (b, 4 output rows), 256 threads: rp=tid>>7 (row pair), cg=(tid>>4)&7
// (cout quad), colb=tid&15 (8-col block). 4 cin-groups of 8.
// xs uses an IN-ROW pad: idx(c) = c + 4*(c>>5) (4 floats inserted every 32), which
// turns the 16-lane 32B-stride ds_read_b128 from a 4-way bank conflict (measured:
// 3.8e7 conflict cycles = 32% of round-3 time) into 2-way = free. float4 chunks
// are 4-aligned and pads sit at 32-boundaries, so chunks never straddle a pad.
// wv[9] hoisted per ci: LDS/block = 2688 b128 (~32K cyc) < FMA 147K cyc/CU -> VALU-bound.
#define CG 8
#define XROW 148                       // 132 cols + 4 pads of 4
__global__ __launch_bounds__(256, 4)
void conv_k(const float* __restrict__ x, const float* __restrict__ wt,
            float* __restrict__ out) {
    __shared__ float xs[CG*6*XROW];    // 7104 floats
    __shared__ float wsh[CG*9*32];     // 2304 floats, layout [ci][k9][co]
    const int b   = blockIdx.x >> 5;
    const int r0  = (blockIdx.x & 31) << 2;       // 4 output rows r0..r0+3
    const int tid = threadIdx.x;
    const int colb = tid & 15;
    const int cg   = (tid >> 4) & 7;
    const int rp   = tid >> 7;
    const int col8 = colb << 3;
    // padded offsets of the three float4 chunks of this thread's 12-col window
    const int po0 = col8     + 4*((col8)    >> 5);
    const int po1 = col8 + 4 + 4*((col8+4) >> 5);
    const int po2 = col8 + 8 + 4*((col8+8) >> 5);
    const int lane32 = tid & 31;
    const int ci_s   = tid >> 5;       // staging: thread's cin
    float acc[2][4][8] = {};
    for (int g = 0; g < 4; ++g) {
        const int c0 = g * CG;
        __syncthreads();   // previous group's compute must finish before restage
        // ---- stage x tile: rows r0-1..r0+4, cols -1..130, zero-padded, XROW layout
        {
            const float* xc = x + ((size_t)b*CIN_ + c0 + ci_s)*HH*WW;
            for (int rr = 0; rr < 6; ++rr) {
                const int gr = r0 - 1 + rr;
                const int rok = ((unsigned)gr < HH);
                const float* xrowp = xc + (size_t)gr*WW - 1;   // +cp -> gc=cp-1
                float* xsrow = xs + (ci_s*6 + rr)*XROW;
                #pragma unroll
                for (int s = 0; s < 5; ++s) {
                    const int cp = s*32 + lane32;
                    if (s == 4 && lane32 >= 4) continue;       // cp >= 132
                    const int gc = cp - 1;
                    float v = 0.f;
                    if (rok && (unsigned)gc < WW) v = xrowp[cp];
                    xsrow[cp + s*4] = v;                       // pad term = 4*(cp>>5) = 4*s
                }
            }
        }
        // ---- stage weights: coalesced float4 copy (wt already [ci][k9][co])
        {
            const float4* src4 = reinterpret_cast<const float4*>(
                wt + (size_t)b*NP + c0*9*32);
            float4* dst4 = reinterpret_cast<float4*>(wsh);
            for (int q = tid; q < CG*9*32/4; q += 256)
                dst4[q] = src4[q];
        }
        __syncthreads();
        for (int ci = 0; ci < CG; ++ci) {
            float4 wv[9];                         // [kh*3+kw] -> 4 couts (quasi-broadcast)
            #pragma unroll
            for (int k9 = 0; k9 < 9; ++k9)
                wv[k9] = *reinterpret_cast<const float4*>(
                    &wsh[(ci*9 + k9)*32 + cg*4]);
            #pragma unroll
            for (int t = 0; t < 4; ++t) {         // input rows (thread window)
                float xrow[12];
                {
                    const float* xbase = xs + (ci*6 + 2*rp + t)*XROW;
                    float4 q0 = *reinterpret_cast<const float4*>(xbase + po0);
                    float4 q1 = *reinterpret_cast<const float4*>(xbase + po1);
                    float4 q2 = *reinterpret_cast<const float4*>(xbase + po2);
                    xrow[0]=q0.x; xrow[1]=q0.y; xrow[2] =q0.z; xrow[3] =q0.w;
                    xrow[4]=q1.x; xrow[5]=q1.y; xrow[6] =q1.z; xrow[7] =q1.w;
                    xrow[8]=q2.x; xrow[9]=q2.y; xrow[10]=q2.z; xrow[11]=q2.w;
                }
                #pragma unroll
                for (int kh = 0; kh < 3; ++kh) {
                    const int ro = t - kh;        // output row this (t,kh) feeds
                    if (ro < 0 || ro > 1) continue;
                    #pragma unroll
                    for (int kw = 0; kw < 3; ++kw) {
                        const float4 w4 = wv[kh*3 + kw];
                        #pragma unroll
                        for (int cl = 0; cl < 8; ++cl) {
                            const float xv = xrow[cl + kw];
                            acc[ro][0][cl] = fmaf(xv, w4.x, acc[ro][0][cl]);
                            acc[ro][1][cl] = fmaf(xv, w4.y, acc[ro][1][cl]);
                            acc[ro][2][cl] = fmaf(xv, w4.z, acc[ro][2][cl]);
                            acc[ro][3][cl] = fmaf(xv, w4.w, acc[ro][3][cl]);
                        }
                    }
                }
            }
        }
    }
    #pragma unroll
    for (int ro = 0; ro < 2; ++ro) {
        const int row = r0 + 2*rp + ro;
        #pragma unroll
        for (int c = 0; c < 4; ++c) {
            const int cout = cg*4 + c;
            float* dst = out + (((size_t)b*COUT_ + cout)*HH + row)*WW + col8;
            *reinterpret_cast<float4*>(dst) =
                make_float4(acc[ro][c][0], acc[ro][c][1], acc[ro][c][2], acc[ro][c][3]);
            *reinterpret_cast<float4*>(dst + 4) =
                make_float4(acc[ro][c][4], acc[ro][c][5], acc[ro][c][6], acc[ro][c][7]);
        }
    }
}

extern "C" void kernel_launch(void* const* d_in, const int* in_sizes, int n_in,
                              void* d_out, int out_size, void* d_ws, size_t ws_size,
                              hipStream_t stream) {
    const float* x    = (const float*)d_in[0];
    const float* cond = (const float*)d_in[1];
    const float* W1   = (const float*)d_in[2];
    const float* b1   = (const float*)d_in[3];
    const float* W2   = (const float*)d_in[4];
    const float* b2   = (const float*)d_in[5];
    float* out = (float*)d_out;

    // Workspace layout (~10.7 MiB):
    //   ht:   HID*B_ floats + 256B prefetch pad  @ 0        (590080 B)
    //   part: KS2*B_*NP floats                   @ 590080   (9437184 B)
    //   wt:   B_*NP floats                       @ 10027264 (1179648 B)
    char* ws = (char*)d_ws;
    float* ht   = (float*)(ws);
    float* part = (float*)(ws + 590080);
    float* wt   = (float*)(ws + 590080 + 9437184);

    hipLaunchKernelGGL(mlp1_k,   dim3(B_*(HID/256)),   dim3(256), 0, stream, cond, W1, b1, ht);
    hipLaunchKernelGGL(mlp2_k,   dim3((NP/64)*KS2),    dim3(64),  0, stream, ht, W2, part);
    hipLaunchKernelGGL(reduce_k, dim3((B_*NP/4)/256),  dim3(256), 0, stream, part, b2, wt);
    hipLaunchKernelGGL(conv_k,   dim3(B_*(HH/4)),      dim3(256), 0, stream, x, wt, out);
}